// Round 4
// baseline (84.237 us; speedup 1.0000x reference)
//
#include <hip/hip_runtime.h>

// PSA "collect": out[n, i*W+j, h, w] = x[n, (i-h+63)*127 + (j-w+63), h, w]
// N=2, H=W=64. Pure permutation-gather (bijection on the valid set).
//
// Block per (n, i, hq): covers G=4 rows h = 4*hq .. 4*hq+3 with FIXED output
// channel block i. dr = i+63-h for the 4 h values are ADJACENT plane groups
// (contiguous ~8MB read region), and writes become 1KB contiguous per output
// channel (4 rows x 256B), consecutive hq-blocks filling adjacent 1KB chunks
// -> DRAM-page-friendly writes (the R3 limiter).
//
// Diagonal LDS tile: tile[j][h'*64+w] = x[n][dr(h')*127 + (j-w+63)][h0+h'][w]
// Load phase: predicated float4 row loads, scalar scatter ds_writes.
// Write phase: ds_read_b128 + global_store_dwordx4, 1KB/channel contiguous.
// LDS = 64*260*4 = 66.5 KB -> 2 blocks/CU (16 waves/CU).

#define H_ 64
#define W_ 64
#define C_ 16129   // 127*127
#define RW_ 127    // 2*W-1
#define G_ 4       // h-rows per block
#define TS_ 260    // floats per j-row: G*64 + 4 pad (1040 B, 16B-aligned)

__global__ __launch_bounds__(512, 4) void collect_kernel(const float* __restrict__ x,
                                                         float* __restrict__ out) {
    __shared__ float tile[H_ * TS_];   // 66560 B

    const int b  = blockIdx.x;
    const int n  = b >> 10;            // 2
    const int i  = (b >> 4) & 63;      // output row block
    const int hq = b & 15;             // fast index: h quarter
    const int h0 = hq * G_;
    const int D0 = i + 63 - h0;        // dr for h' = 0

    const int t = threadIdx.x;

    const float* __restrict__ basen = x + (size_t)n * C_ * (H_ * W_);

    // ---- load phase: 4 h-planes x 127 rows x 16 f4 slots = 8128 slots ----
    // padded iteration space 8192 = 16 * 512
    #pragma unroll
    for (int k = 0; k < 16; ++k) {
        const int idx = t + (k << 9);
        const int hp  = idx >> 11;         // h' in [0,4)
        const int rem = idx & 2047;
        if (rem < RW_ * 16) {
            const int cc = rem >> 4;
            const int s4 = rem & 15;
            // used w range for row cc: j = cc + w - 63 must be in [0,64)
            const int w0 = max(0, 63 - cc);
            const int w1 = min(63, 126 - cc);
            if (s4 >= (w0 >> 2) && s4 <= (w1 >> 2)) {
                const float* src = basen
                    + (size_t)(D0 - hp) * (RW_ * H_ * W_)   // plane group dr
                    + (size_t)cc * (H_ * W_)                // plane within group
                    + (h0 + hp) * W_ + s4 * 4;              // row h, slot
                const float4 v = *reinterpret_cast<const float4*>(src);
                const int jb = cc + s4 * 4 - 63;
                const float* vf = reinterpret_cast<const float*>(&v);
                #pragma unroll
                for (int e = 0; e < 4; ++e) {
                    const int j = jb + e;
                    if ((unsigned)j < (unsigned)H_) {
                        tile[j * TS_ + (hp << 6) + s4 * 4 + e] = vf[e];
                    }
                }
            }
        }
    }
    __syncthreads();

    // ---- write phase: channel j = t>>3, f4 slots (t&7) + 8k, k<8 ----
    // per channel: G*64 = 256 floats = 1KB contiguous in output
    const int j  = t >> 3;
    const int s0 = t & 7;
    float* __restrict__ dst =
        out + ((size_t)(n * (H_ * W_) + i * W_ + j) << 12) + (h0 << 6);
    const float* __restrict__ trow = &tile[j * TS_];
    #pragma unroll
    for (int k = 0; k < 8; ++k) {
        const int slot = s0 + (k << 3);
        *reinterpret_cast<float4*>(dst + slot * 4) =
            *reinterpret_cast<const float4*>(trow + slot * 4);
    }
}

extern "C" void kernel_launch(void* const* d_in, const int* in_sizes, int n_in,
                              void* d_out, int out_size, void* d_ws, size_t ws_size,
                              hipStream_t stream) {
    const float* x = (const float*)d_in[0];
    float* out = (float*)d_out;
    // grid = N * 64(i) * 16(hq) = 2048 blocks of 512 threads
    collect_kernel<<<dim3(2048), dim3(512), 0, stream>>>(x, out);
}

// Round 5
// 70.061 us; speedup vs baseline: 1.2023x; 1.2023x over previous
//
#include <hip/hip_runtime.h>

// PSA "collect": out[n, i*W+j, h, w] = x[n, (i-h+63)*127 + (j-w+63), h, w]
// N=2, H=W=64. Pure permutation-gather (bijection on the valid set).
//
// Block body = R3 (winner): block handles one (n, s, h), i=(h+s)&63,
// dr = i-h+63 in {s+63, s-1}. Diagonal LDS tile tile[j][w], predicated f4
// loads, vectorized stores. LDS 17.4 KB -> 8 blocks/CU.
//
// NEW: grid order = 32x32 (s,h) SUPERTILES (h fast within tile).
//  - reads:  32 consecutive h-rows of each plane-group co-resident
//            -> 8 KB contiguous read chunks (was dense via s-groups in R3).
//  - writes: anti-diagonals i=h+s=const inside the tile give ~16 consecutive
//            h-rows per output panel -> ~4 KB contiguous write chunks
//            (was 256 B device-wide scatter in R3 — the presumed limiter).

#define H_ 64
#define W_ 64
#define C_ 16129   // 127*127
#define RW_ 127    // 2*W-1
#define TS_ 68     // tile row stride in floats

__global__ __launch_bounds__(256, 8) void collect_kernel(const float* __restrict__ x,
                                                         float* __restrict__ out) {
    __shared__ float tile[H_ * TS_];   // diagonal layout tile[j][w]

    const int b  = blockIdx.x;
    const int n  = b >> 12;                 // batch
    const int st = (b >> 11) & 1;          // s-tile (2 tiles of 32)
    const int ht = (b >> 10) & 1;          // h-tile
    const int s  = st * 32 + ((b >> 5) & 31);
    const int h  = ht * 32 + (b & 31);     // fast: spatial row
    const int i  = (h + s) & 63;
    const int dr = i - h + 63;             // in {s+63, s-1}, always [0,126]

    const int t = threadIdx.x;

    // x[n][dr*127 + cc][h][w] = src[cc*4096 + w]
    const float* __restrict__ src =
        x + (((size_t)n * C_ + (size_t)dr * RW_) * H_ + h) * W_;

    // ---- load phase: 127 rows x 16 float4 slots, predicated to used span ----
    #pragma unroll
    for (int k = 0; k < 8; ++k) {
        const int idx = t + k * 256;
        if (idx < RW_ * 16) {
            const int cc = idx >> 4;
            const int s4 = idx & 15;
            // used w range for row cc: j = cc + w - 63 must be in [0,64)
            const int w0 = max(0, 63 - cc);
            const int w1 = min(63, 126 - cc);
            if (s4 >= (w0 >> 2) && s4 <= (w1 >> 2)) {
                const float4 v =
                    *reinterpret_cast<const float4*>(src + cc * (H_ * W_) + s4 * 4);
                const int jb = cc + s4 * 4 - 63;   // j for element e=0
                const float* vf = reinterpret_cast<const float*>(&v);
                #pragma unroll
                for (int e = 0; e < 4; ++e) {
                    const int j = jb + e;
                    if ((unsigned)j < (unsigned)H_) {
                        tile[j * TS_ + s4 * 4 + e] = vf[e];
                    }
                }
            }
        }
    }
    __syncthreads();

    // ---- write phase: vectorized. thread t -> (j0 = t>>4, w4 = t&15) ----
    const int w4 = t & 15;
    const int j0 = t >> 4;
    float* __restrict__ dstbase =
        out + (((size_t)n * (H_ * W_) + (size_t)i * W_) * H_ + h) * W_ + w4 * 4;

    #pragma unroll
    for (int k = 0; k < 4; ++k) {
        const int j = j0 + k * 16;
        *reinterpret_cast<float4*>(dstbase + (size_t)j * (H_ * W_)) =
            *reinterpret_cast<const float4*>(&tile[j * TS_ + w4 * 4]);
    }
}

extern "C" void kernel_launch(void* const* d_in, const int* in_sizes, int n_in,
                              void* d_out, int out_size, void* d_ws, size_t ws_size,
                              hipStream_t stream) {
    const float* x = (const float*)d_in[0];
    float* out = (float*)d_out;
    collect_kernel<<<dim3(8192), dim3(256), 0, stream>>>(x, out);
}